// Round 2
// baseline (877.686 us; speedup 1.0000x reference)
//
#include <hip/hip_runtime.h>
#include <math.h>

// Choquet tree: B=16 children/node, DEPTH=6, NPAIR=120 (triu k=1), 136 logits/node.
// Per node: m = softmax(theta); out = sum(m[:16]*x) + sum(m[16:]*min(x[i],x[j]))
// Computed unnormalized: (sum w*x + sum w*min) / sum w, w = exp(theta).
//
// R2: LDS-staged theta/children via global_load_lds (width 16). Per-thread
// row reads were 64-line wave transactions (stride 544 B); staging makes all
// global traffic 8-line coalesced wave transactions.

#define BFAC 16
#define NPAIR 120
#define NW 136
#define TILE 64

typedef const __attribute__((address_space(1))) void* gptr_t;
typedef __attribute__((address_space(3))) void* lptr_t;

__device__ __forceinline__ float choquet_math(const float* __restrict__ ch,
                                              const float* __restrict__ th) {
    const float4* ch4 = reinterpret_cast<const float4*>(ch);
    const float4* th4 = reinterpret_cast<const float4*>(th);
    float x[BFAC];
#pragma unroll
    for (int k = 0; k < 4; ++k) {
        float4 v = ch4[k];
        x[4 * k + 0] = v.x; x[4 * k + 1] = v.y;
        x[4 * k + 2] = v.z; x[4 * k + 3] = v.w;
    }
    float acc0 = 0.f, acc1 = 0.f, den0 = 0.f, den1 = 0.f;
    // singletons: logits 0..15
#pragma unroll
    for (int c = 0; c < 4; ++c) {
        float4 v = th4[c];
        float w0 = __expf(v.x), w1 = __expf(v.y), w2 = __expf(v.z), w3 = __expf(v.w);
        den0 += w0 + w2;
        den1 += w1 + w3;
        acc0 += w0 * x[4 * c + 0] + w2 * x[4 * c + 2];
        acc1 += w1 * x[4 * c + 1] + w3 * x[4 * c + 3];
    }
    // pairs: logits 16..135, triu order (0,1),(0,2)..(0,15),(1,2)..(14,15)
    int p = BFAC;
    float4 v;
#pragma unroll
    for (int i = 0; i < BFAC - 1; ++i) {
#pragma unroll
        for (int j = i + 1; j < BFAC; ++j) {
            int c = p & 3;
            if (c == 0) v = th4[p >> 2];
            float t = (c == 0) ? v.x : (c == 1) ? v.y : (c == 2) ? v.z : v.w;
            float w = __expf(t);
            float mn = fminf(x[i], x[j]);
            if (p & 1) { den1 += w; acc1 += w * mn; }
            else       { den0 += w; acc0 += w * mn; }
            ++p;
        }
    }
    return (acc0 + acc1) / (den0 + den1);
}

// Async-stage one 64-node tile (theta: 34 chunks of 64 float4; x: 4 chunks)
// into LDS. Contiguous global -> contiguous LDS; lds dest = uniform base +
// lane*16, exactly the supported global_load_lds pattern.
__device__ __forceinline__ void stage_tile(const float* __restrict__ in,
                                           const float* __restrict__ theta,
                                           long node_base,
                                           float* s_th, float* s_x,
                                           int wave, int lane) {
    const float* g_th = theta + node_base * NW;
    const float* g_x  = in + node_base * BFAC;
#pragma unroll
    for (int k0 = 0; k0 < 9; ++k0) {
        int k = wave + 4 * k0;           // 34 chunks over 4 waves
        if (k < 34) {
            __builtin_amdgcn_global_load_lds((gptr_t)(g_th + k * 256 + lane * 4),
                                             (lptr_t)(s_th + k * 256),
                                             16, 0, 0);
        }
    }
    __builtin_amdgcn_global_load_lds((gptr_t)(g_x + wave * 256 + lane * 4),
                                     (lptr_t)(s_x + wave * 256),
                                     16, 0, 0);
}

// 256 nodes per 256-thread block; 4 tiles of 64 nodes, double-buffered LDS.
// Wave t computes tile t while all waves async-stage tile t+1.
// LDS: 2*(34816 + 4096) = 77824 B -> 2 blocks/CU, 8 waves/CU.
__global__ void __launch_bounds__(256)
choquet_staged(const float* __restrict__ in, const float* __restrict__ theta,
               float* __restrict__ out) {
    __shared__ __align__(16) float s_th[2][TILE * NW];
    __shared__ __align__(16) float s_x[2][TILE * BFAC];
    const int tid = threadIdx.x;
    const int wave = tid >> 6, lane = tid & 63;
    const long base = (long)blockIdx.x * 256;

    stage_tile(in, theta, base, s_th[0], s_x[0], wave, lane);
#pragma unroll 1
    for (int t = 0; t < 4; ++t) {
        __syncthreads();  // per-wave vmcnt(0) drain => tile t resident
        if (t < 3)
            stage_tile(in, theta, base + (t + 1) * TILE,
                       s_th[(t + 1) & 1], s_x[(t + 1) & 1], wave, lane);
        if (wave == t) {
            const float* xr = &s_x[t & 1][lane * BFAC];
            const float* tr = &s_th[t & 1][lane * NW];
            out[base + t * TILE + lane] = choquet_math(xr, tr);
        }
    }
}

// Levels 4(256 nodes) + 5(16) + 6(1) fused in one block via LDS.
__global__ void __launch_bounds__(256)
choquet_tail_kernel(const float* __restrict__ in,
                    const float* __restrict__ th4_,
                    const float* __restrict__ th5_,
                    const float* __restrict__ th6_,
                    float* __restrict__ out) {
    __shared__ __align__(16) float l4[256];
    __shared__ __align__(16) float l5[16];
    int t = threadIdx.x;
    l4[t] = choquet_math(in + (size_t)t * BFAC, th4_ + (size_t)t * NW);
    __syncthreads();
    if (t < 16) l5[t] = choquet_math(l4 + t * BFAC, th5_ + (size_t)t * NW);
    __syncthreads();
    if (t == 0) out[0] = choquet_math(l5, th6_);
}

extern "C" void kernel_launch(void* const* d_in, const int* in_sizes, int n_in,
                              void* d_out, int out_size, void* d_ws, size_t ws_size,
                              hipStream_t stream) {
    const float* x   = (const float*)d_in[0];
    const float* th1 = (const float*)d_in[1];
    const float* th2 = (const float*)d_in[2];
    const float* th3 = (const float*)d_in[3];
    const float* th4 = (const float*)d_in[4];
    const float* th5 = (const float*)d_in[5];
    const float* th6 = (const float*)d_in[6];
    float* out = (float*)d_out;

    // workspace (floats): level1 out 1048576 | level2 out 65536 | level3 out 4096
    float* ws0 = (float*)d_ws;
    float* ws1 = ws0 + 1048576;
    float* ws2 = ws1 + 65536;

    choquet_staged<<<4096, 256, 0, stream>>>(x, th1, ws0);   // level 1: 16^5 nodes
    choquet_staged<<<256, 256, 0, stream>>>(ws0, th2, ws1);  // level 2: 65536
    choquet_staged<<<16, 256, 0, stream>>>(ws1, th3, ws2);   // level 3: 4096
    choquet_tail_kernel<<<1, 256, 0, stream>>>(ws2, th4, th5, th6, out);
}